// Round 5
// baseline (253.528 us; speedup 1.0000x reference)
//
#include <hip/hip_runtime.h>
#include <math.h>
#include <stdint.h>

#define N512 512

typedef __attribute__((ext_vector_type(8))) short short8;
typedef __attribute__((ext_vector_type(4))) float floatx4;

#define VMCNT0 asm volatile("s_waitcnt vmcnt(0)" ::: "memory")

__device__ __forceinline__ short f2bf(float f) {
    uint32_t u = __float_as_uint(f);
    uint32_t r = u + 0x7fffu + ((u >> 16) & 1u);
    return (short)(r >> 16);
}

// cheap round-half-up (2 VALU): fine vs 0.109 threshold
__device__ __forceinline__ short f2bf_fast(float f) {
    return (short)((__float_as_uint(f) + 0x8000u) >> 16);
}

__device__ __forceinline__ void gload_lds16(const void* g, void* l) {
    __builtin_amdgcn_global_load_lds(
        (const __attribute__((address_space(1))) void*)g,
        (__attribute__((address_space(3))) void*)l,
        16, 0, 0);
}

// Parity-split DCT matrix (butterfly): for n in [0,256), j in [0,256):
//   Me[n][j] = M[n][2j], Mo[n][j] = M[n][2j+1]
// where M[n,k] = s_k cos(pi k (2n+1) / (2N)).
// Butterfly identity: M[511-n,k] = (-1)^k M[n,k].
__global__ __launch_bounds__(256) void build_idct_matrix_bf16(short* __restrict__ Mb) {
    int idx = blockIdx.x * 256 + threadIdx.x;     // 0..131071
    int par = idx >> 16;                          // 0: even k, 1: odd k
    int e = idx & 65535;
    int n = e >> 8;                               // 0..255
    int j = e & 255;                              // 0..255
    int k = 2 * j + par;
    int jr = (k * (2 * n + 1)) & (4 * N512 - 1);
    float theta = (float)jr * (3.14159265358979323846f / (2.0f * (float)N512));
    float s = (k == 0) ? 0.044194173824159216f : 0.0625f;
    Mb[par * 65536 + n * 256 + j] = f2bf(s * cosf(theta));
}

// ---------------------------------------------------------------------------
// Stage 1 (butterfly): for n in [0,256):
//   P[n][h] = sum_j Me[n,j] * X[h,2j],  Q[n][h] = sum_j Mo[n,j] * X[h,2j+1]
//   Tt[n][h] = P+Q ; Tt[511-n][h] = P-Q
// Output stored h-parity-split for stage 2: Tte[n][u]=Tt[n][2u] (512x256),
// Tto likewise, so s2 can DMA-stage both operands.
// Block: 128 n-rows (bm0 in {0,128}) x 128 h-cols. 4 waves, 64x64 out each,
// TWO acc sets (P,Q). K-loop: 4 steps of BK=64 (j-dim). Verified swizzle/
// fragment math carried over unchanged.
// ---------------------------------------------------------------------------
__global__ __launch_bounds__(256) void gemm_s1(const short* __restrict__ Mb,
                                               const float* __restrict__ Xg,
                                               short* __restrict__ Tg) {
    __shared__ __align__(16) short lds[32768];   // Ae|Ao|Be|Bo, 8192 each
    short* ldsAe = lds;
    short* ldsAo = lds + 8192;
    short* ldsBe = lds + 16384;
    short* ldsBo = lds + 24576;

    const int t = threadIdx.x;
    const int w = t >> 6;          // wave 0..3
    const int l = t & 63;
    const int q = (l >> 4) & 3;
    const int r = l & 15;

    const int bn0 = blockIdx.x * 128;   // h-tile
    const int bm0 = blockIdx.y * 128;   // n-tile within [0,256)
    const int wm0 = (w >> 1) * 64;
    const int wn0 = (w & 1) * 64;

    const float* Xs = Xg + ((long)blockIdx.z << 18);
    short* Te = Tg + ((long)blockIdx.z << 18);   // Tte; Tto at +131072

    const short* Me = Mb;
    const short* Mo = Mb + 65536;

    // A-DMA mapping (verified): chunk=8 rows, lane covers row l>>3,
    // pre-swizzled granule (l&7)^(l>>3) on the global address.
    const int rsub = l >> 3;
    const int glog = (l & 7) ^ rsub;

    // X staging: pass p -> row p*16+(t>>4); thread covers 8 consecutive
    // floats (2 float4) at col kt*128 + (t&15)*8 -> je/jo = kt*64+(t&15)*4..+3
    const int brow = t >> 4;
    const int bcol = t & 15;
    const int bg = bcol >> 1;     // j-granule 0..7
    const int bh = bcol & 1;      // half of granule

    floatx4 accP[4][4] = {};
    floatx4 accQ[4][4] = {};

    for (int kt = 0; kt < 4; ++kt) {
        const int k0 = kt * 64;               // j-base
        // A: Me,Mo tiles via DMA (8 instr/wave)
#pragma unroll
        for (int i = 0; i < 4; ++i) {
            const int ch = w * 4 + i;
            const int arow = bm0 + ch * 8 + rsub;
            gload_lds16(Me + arow * 256 + k0 + glog * 8, ldsAe + ch * 512);
            gload_lds16(Mo + arow * 256 + k0 + glog * 8, ldsAo + ch * 512);
        }
        // X: 16 coalesced float4 loads (128 rows x 128 orig-cols)
        float4 va[8], vb[8];
#pragma unroll
        for (int p = 0; p < 8; ++p) {
            const int row = bn0 + p * 16 + brow;
            const float* base = Xs + ((long)row << 9) + kt * 128 + bcol * 8;
            va[p] = *(const float4*)(base);
            vb[p] = *(const float4*)(base + 4);
        }
        VMCNT0;
        // parity split in-register -> swizzled ds_write (same formula as ever)
#pragma unroll
        for (int p = 0; p < 8; ++p) {
            const int rt = p * 16 + brow;
            short4 ev, od;
            ev.x = f2bf_fast(va[p].x); ev.y = f2bf_fast(va[p].z);
            ev.z = f2bf_fast(vb[p].x); ev.w = f2bf_fast(vb[p].z);
            od.x = f2bf_fast(va[p].y); od.y = f2bf_fast(va[p].w);
            od.z = f2bf_fast(vb[p].y); od.w = f2bf_fast(vb[p].w);
            const int addr = rt * 64 + ((bg ^ (rt & 7)) * 8) + bh * 4;
            *(short4*)(ldsBe + addr) = ev;
            *(short4*)(ldsBo + addr) = od;
        }
        __syncthreads();
#pragma unroll
        for (int kk = 0; kk < 2; ++kk) {
            const int c = kk * 4 + q;
            const int goff = ((c ^ (r & 7)) * 8);
            short8 af[4], bf4[4];
            // even parity -> accP
#pragma unroll
            for (int i = 0; i < 4; ++i) {
                af[i]  = *(const short8*)(ldsAe + (wm0 + i * 16 + r) * 64 + goff);
                bf4[i] = *(const short8*)(ldsBe + (wn0 + i * 16 + r) * 64 + goff);
            }
#pragma unroll
            for (int i = 0; i < 4; ++i)
#pragma unroll
                for (int j = 0; j < 4; ++j)
                    accP[i][j] = __builtin_amdgcn_mfma_f32_16x16x32_bf16(
                        af[i], bf4[j], accP[i][j], 0, 0, 0);
            // odd parity -> accQ
#pragma unroll
            for (int i = 0; i < 4; ++i) {
                af[i]  = *(const short8*)(ldsAo + (wm0 + i * 16 + r) * 64 + goff);
                bf4[i] = *(const short8*)(ldsBo + (wn0 + i * 16 + r) * 64 + goff);
            }
#pragma unroll
            for (int i = 0; i < 4; ++i)
#pragma unroll
                for (int j = 0; j < 4; ++j)
                    accQ[i][j] = __builtin_amdgcn_mfma_f32_16x16x32_bf16(
                        af[i], bf4[j], accQ[i][j], 0, 0, 0);
        }
        __syncthreads();
    }

    // epilogue: n in [0,256): Tt[n]=P+Q, Tt[511-n]=P-Q; h-parity-split store.
#pragma unroll
    for (int i = 0; i < 4; ++i) {
        const int nb = bm0 + wm0 + i * 16 + q * 4;
#pragma unroll
        for (int j = 0; j < 4; ++j) {
            const int h = bn0 + wn0 + j * 16 + r;
            short* dst = Te + (h & 1) * 131072 + (h >> 1);
#pragma unroll
            for (int rg = 0; rg < 4; ++rg) {
                const int n = nb + rg;
                const float p = accP[i][j][rg], qq = accQ[i][j][rg];
                dst[n * 256] = f2bf(p + qq);
                dst[(511 - n) * 256] = f2bf(p - qq);
            }
        }
    }
}

// ---------------------------------------------------------------------------
// Stage 2 (butterfly): for m in [0,256):
//   R[m][n] = sum_u Me[m,u] * Tte[n,u],  S[m][n] = sum_u Mo[m,u] * Tto[n,u]
//   Out[m][n] = R+S ; Out[511-m][n] = R-S   (fp32 out)
// All four operand tiles DMA-staged (16 instr/wave/step).
// ---------------------------------------------------------------------------
__global__ __launch_bounds__(256) void gemm_s2(const short* __restrict__ Mb,
                                               const short* __restrict__ Tg,
                                               float* __restrict__ Cg) {
    __shared__ __align__(16) short lds[32768];
    short* ldsAe = lds;
    short* ldsAo = lds + 8192;
    short* ldsBe = lds + 16384;
    short* ldsBo = lds + 24576;

    const int t = threadIdx.x;
    const int w = t >> 6;
    const int l = t & 63;
    const int q = (l >> 4) & 3;
    const int r = l & 15;

    const int bn0 = blockIdx.x * 128;   // output col tile (rows of Tte/Tto)
    const int bm0 = blockIdx.y * 128;   // m-tile within [0,256)
    const int wm0 = (w >> 1) * 64;
    const int wn0 = (w & 1) * 64;

    const short* Te = Tg + ((long)blockIdx.z << 18);
    float* C = Cg + ((long)blockIdx.z << 18);

    const short* Me = Mb;
    const short* Mo = Mb + 65536;

    const int rsub = l >> 3;
    const int glog = (l & 7) ^ rsub;

    floatx4 accR[4][4] = {};
    floatx4 accS[4][4] = {};

    for (int kt = 0; kt < 4; ++kt) {
        const int k0 = kt * 64;
#pragma unroll
        for (int i = 0; i < 4; ++i) {
            const int ch = w * 4 + i;
            const int arow = bm0 + ch * 8 + rsub;
            const int brw  = bn0 + ch * 8 + rsub;
            gload_lds16(Me + arow * 256 + k0 + glog * 8, ldsAe + ch * 512);
            gload_lds16(Mo + arow * 256 + k0 + glog * 8, ldsAo + ch * 512);
            gload_lds16(Te + brw * 256 + k0 + glog * 8, ldsBe + ch * 512);
            gload_lds16(Te + 131072 + brw * 256 + k0 + glog * 8, ldsBo + ch * 512);
        }
        VMCNT0;
        __syncthreads();
#pragma unroll
        for (int kk = 0; kk < 2; ++kk) {
            const int c = kk * 4 + q;
            const int goff = ((c ^ (r & 7)) * 8);
            short8 af[4], bf4[4];
#pragma unroll
            for (int i = 0; i < 4; ++i) {
                af[i]  = *(const short8*)(ldsAe + (wm0 + i * 16 + r) * 64 + goff);
                bf4[i] = *(const short8*)(ldsBe + (wn0 + i * 16 + r) * 64 + goff);
            }
#pragma unroll
            for (int i = 0; i < 4; ++i)
#pragma unroll
                for (int j = 0; j < 4; ++j)
                    accR[i][j] = __builtin_amdgcn_mfma_f32_16x16x32_bf16(
                        af[i], bf4[j], accR[i][j], 0, 0, 0);
#pragma unroll
            for (int i = 0; i < 4; ++i) {
                af[i]  = *(const short8*)(ldsAo + (wm0 + i * 16 + r) * 64 + goff);
                bf4[i] = *(const short8*)(ldsBo + (wn0 + i * 16 + r) * 64 + goff);
            }
#pragma unroll
            for (int i = 0; i < 4; ++i)
#pragma unroll
                for (int j = 0; j < 4; ++j)
                    accS[i][j] = __builtin_amdgcn_mfma_f32_16x16x32_bf16(
                        af[i], bf4[j], accS[i][j], 0, 0, 0);
        }
        __syncthreads();
    }

    // epilogue: Out[m]=R+S, Out[511-m]=R-S (fp32, 64B row segments)
#pragma unroll
    for (int i = 0; i < 4; ++i) {
        const int mb = bm0 + wm0 + i * 16 + q * 4;
#pragma unroll
        for (int j = 0; j < 4; ++j) {
            const int n = bn0 + wn0 + j * 16 + r;
#pragma unroll
            for (int rg = 0; rg < 4; ++rg) {
                const int m = mb + rg;
                const float rr = accR[i][j][rg], ss = accS[i][j][rg];
                C[(long)m * N512 + n] = rr + ss;
                C[(long)(511 - m) * N512 + n] = rr - ss;
            }
        }
    }
}

extern "C" void kernel_launch(void* const* d_in, const int* in_sizes, int n_in,
                              void* d_out, int out_size, void* d_ws, size_t ws_size,
                              hipStream_t stream) {
    const float* X = (const float*)d_in[0];
    float* out = (float*)d_out;

    const long plane = (long)N512 * N512;          // 262144
    const int slices = in_sizes[0] / (int)plane;   // 96

    short* Mb = (short*)d_ws;                      // Me|Mo: 131072 shorts, 256 KB
    short* Tt = Mb + 131072;                       // per slice: Tte|Tto = 262144 shorts

    long avail = (long)ws_size - 262144;           // bytes after Me/Mo
    int chunk = (int)(avail / (plane * 2));        // 512 KB per slice
    if (chunk > slices) chunk = slices;
    if (chunk < 1) chunk = 1;

    build_idct_matrix_bf16<<<dim3(512), dim3(256), 0, stream>>>(Mb);

    for (int s0 = 0; s0 < slices; s0 += chunk) {
        int c = (s0 + chunk <= slices) ? chunk : (slices - s0);
        // stage 1: Tte/Tto[z] from X[z] (butterfly over n)
        gemm_s1<<<dim3(4, 2, c), dim3(256), 0, stream>>>(
            Mb, X + (long)s0 * plane, Tt);
        // stage 2: Out[z] from Tte/Tto[z] (butterfly over m)
        gemm_s2<<<dim3(4, 2, c), dim3(256), 0, stream>>>(
            Mb, Tt, out + (long)s0 * plane);
    }
}